// Round 5
// baseline (229.136 us; speedup 1.0000x reference)
//
#include <hip/hip_runtime.h>
#include <math.h>

// B=4, H=W=64, C=256, Ck=32, N=4096, M=B*N=16384
// ws: fg bf16 [16384][64] (f=cols0..31, g=cols32..63)
//   | hmt bf16 [4][256][4096] (channel-major)
//   | wT bf16 [576][256] (0..31 Wf^T, 32..63 Wg^T, 64..319 Wh^T, 320..575 Wv^T)
//   | lpart f32 [S][16384] | obf bf16 [S][16384][256] (per-split normalized)

typedef unsigned short u16;
typedef __attribute__((ext_vector_type(8))) short  bf16x8;
typedef __attribute__((ext_vector_type(4))) float  f32x4;

__device__ inline u16 f2bf(float x) {
    unsigned u = __float_as_uint(x);
    unsigned r = (u + 0x7fffu + ((u >> 16) & 1u)) >> 16;
    return (u16)r;
}

__device__ inline float bf2f(short s) {
    return __uint_as_float(((unsigned)(u16)s) << 16);
}

__device__ inline bf16x8 cvt8(float4 a, float4 b) {
    bf16x8 r;
    r[0] = (short)f2bf(a.x); r[1] = (short)f2bf(a.y);
    r[2] = (short)f2bf(a.z); r[3] = (short)f2bf(a.w);
    r[4] = (short)f2bf(b.x); r[5] = (short)f2bf(b.y);
    r[6] = (short)f2bf(b.z); r[7] = (short)f2bf(b.w);
    return r;
}

// ---------------------------------------------------------------------------
// prep: pack weights transposed to bf16.  wT[n][k], n = concat col index.
// ---------------------------------------------------------------------------
__global__ __launch_bounds__(256) void prep_w(
    const float* __restrict__ Wf, const float* __restrict__ Wg,
    const float* __restrict__ Wh, const float* __restrict__ Wv,
    u16* __restrict__ wT)
{
    const int n = blockIdx.x;
    const int k = threadIdx.x;
    float v;
    if (n < 32)        v = Wf[(size_t)k * 32 + n];
    else if (n < 64)   v = Wg[(size_t)k * 32 + n - 32];
    else if (n < 320)  v = Wh[(size_t)k * 256 + n - 64];
    else               v = Wv[(size_t)k * 256 + n - 320];
    wT[(size_t)n * 256 + k] = f2bf(v);
}

// ---------------------------------------------------------------------------
// proj: Y[16384, 320] = x @ [Wf|Wg|Wh] + bias, bf16 MFMA, no LDS.
// block = 32 rows; wave w = cols w*80..+79 (5 n-tiles).
// cols 0..63 -> fg row-major; cols 64..319 -> hmt channel-major (8B stores).
// ---------------------------------------------------------------------------
__global__ __launch_bounds__(256) void proj_mfma(
    const float* __restrict__ x, const u16* __restrict__ wT,
    const float* __restrict__ bfv, const float* __restrict__ bgv,
    const float* __restrict__ bhv,
    u16* __restrict__ fg, u16* __restrict__ hmt)
{
    const int t    = threadIdx.x;
    const int w    = t >> 6;
    const int lane = t & 63;
    const int quad = lane >> 4;
    const int l16  = lane & 15;
    const int m0   = blockIdx.x * 32;
    const int wb   = w * 80;

    f32x4 acc[2][5];
#pragma unroll
    for (int mt = 0; mt < 2; ++mt)
#pragma unroll
        for (int nt = 0; nt < 5; ++nt)
#pragma unroll
            for (int r = 0; r < 4; ++r) acc[mt][nt][r] = 0.f;

#pragma unroll 2
    for (int ks = 0; ks < 8; ++ks) {
        bf16x8 afrag[2];
#pragma unroll
        for (int mt = 0; mt < 2; ++mt) {
            const float* xp = x + (size_t)(m0 + mt * 16 + l16) * 256 +
                              ks * 32 + quad * 8;
            float4 a0 = *reinterpret_cast<const float4*>(xp);
            float4 a1 = *reinterpret_cast<const float4*>(xp + 4);
            afrag[mt] = cvt8(a0, a1);
        }
#pragma unroll
        for (int nt = 0; nt < 5; ++nt) {
            bf16x8 bfrag = *reinterpret_cast<const bf16x8*>(
                wT + (size_t)(wb + nt * 16 + l16) * 256 + ks * 32 + quad * 8);
#pragma unroll
            for (int mt = 0; mt < 2; ++mt)
                acc[mt][nt] = __builtin_amdgcn_mfma_f32_16x16x32_bf16(
                    afrag[mt], bfrag, acc[mt][nt], 0, 0, 0);
        }
    }

    const int bb   = m0 >> 12;
    const int npix = m0 & 4095;
#pragma unroll
    for (int nt = 0; nt < 5; ++nt) {
        int col = wb + nt * 16 + l16;
        if (col < 64) {
            float bias = (col < 32) ? bfv[col] : bgv[col - 32];
#pragma unroll
            for (int mt = 0; mt < 2; ++mt) {
                int row = m0 + mt * 16 + quad * 4;
#pragma unroll
                for (int r = 0; r < 4; ++r)
                    fg[(size_t)(row + r) * 64 + col] =
                        f2bf(acc[mt][nt][r] + bias);
            }
        } else {
            int c = col - 64;
            float bias = bhv[c];
#pragma unroll
            for (int mt = 0; mt < 2; ++mt) {
                int n0 = npix + mt * 16 + quad * 4;
                ushort4 hv;
                hv.x = f2bf(acc[mt][nt][0] + bias);
                hv.y = f2bf(acc[mt][nt][1] + bias);
                hv.z = f2bf(acc[mt][nt][2] + bias);
                hv.w = f2bf(acc[mt][nt][3] + bias);
                *reinterpret_cast<ushort4*>(
                    hmt + ((size_t)bb * 256 + c) * 4096 + n0) = hv;
            }
        }
    }
}

// ---------------------------------------------------------------------------
// Flash attention v3 (no-max softmax, split-K, single barrier/iter):
//  block: (b, qt, ks). 64 queries, 128-key tiles, nkt = 32>>ksl tiles.
//  F B-frags + V B-frags loaded DIRECTLY from global (L2-resident) — no
//  async staging, so barriers carry only the P dependency.
//  P double-buffered in LDS, layout [kblk(16)][row(64)][8] so PV A-frag
//  ds_read_b128 is quarter-wave-contiguous (conflict-free) and exp-phase
//  u16 writes are <=2-way (free).
//  Emits per-split NORMALIZED o (bf16) + l partials; final combines.
// ---------------------------------------------------------------------------
__global__ __launch_bounds__(256) void attn3(
    const u16* __restrict__ fg, const u16* __restrict__ hmt,
    u16* __restrict__ obf, float* __restrict__ lpart, int ksl)
{
    __shared__ u16 pl[2][8192];   // [kblk][row][8] per buffer
    __shared__ float lfin[64];

    const int t    = threadIdx.x;
    const int w    = t >> 6;
    const int lane = t & 63;
    const int quad = lane >> 4;
    const int l16  = lane & 15;
    const int ks   = blockIdx.x & ((1 << ksl) - 1);
    const int qt   = (blockIdx.x >> ksl) & 63;
    const int b    = blockIdx.x >> (ksl + 6);
    const int nkt  = 32 >> ksl;
    const int kt0  = ks * nkt;

    const size_t fg_base = (size_t)b * 4096 * 64;
    const size_t hm_base = (size_t)b * 256 * 4096;

    // G A-frag: row qt*64 + w*16 + l16, ch quad*8..+7 (g = fg cols 32..63)
    const bf16x8 gfrag = *reinterpret_cast<const bf16x8*>(
        fg + fg_base + (size_t)(qt * 64 + w * 16 + l16) * 64 + 32 + quad * 8);

    f32x4 oacc[4][4];
#pragma unroll
    for (int mt = 0; mt < 4; ++mt)
#pragma unroll
        for (int nt = 0; nt < 4; ++nt)
#pragma unroll
            for (int r = 0; r < 4; ++r) oacc[mt][nt][r] = 0.f;

    float lsum[4] = {0.f, 0.f, 0.f, 0.f};
    const f32x4 zero4 = {0.f, 0.f, 0.f, 0.f};

    for (int it = 0; it < nkt; ++it) {
        const int kt  = kt0 + it;
        const int buf = it & 1;

        // V B-frags direct from global (in flight through S phase, drained
        // by the barrier's vmcnt wait)
        bf16x8 vbr[4][4];
#pragma unroll
        for (int nt = 0; nt < 4; ++nt)
#pragma unroll
            for (int kh = 0; kh < 4; ++kh)
                vbr[nt][kh] = *reinterpret_cast<const bf16x8*>(
                    hmt + hm_base + (size_t)(w * 64 + nt * 16 + l16) * 4096 +
                    kt * 128 + kh * 32 + quad * 8);

        // ---- S = G @ F^T, rows w*16..+15, 128 keys; F direct from L2 ----
        f32x4 sacc[8];
#pragma unroll
        for (int ct = 0; ct < 8; ++ct) {
            bf16x8 fb = *reinterpret_cast<const bf16x8*>(
                fg + fg_base + (size_t)(kt * 128 + ct * 16 + l16) * 64 +
                quad * 8);
            sacc[ct] = __builtin_amdgcn_mfma_f32_16x16x32_bf16(
                gfrag, fb, zero4, 0, 0, 0);
        }

        // ---- p = exp(s), write P[kblk][row][8], accumulate l ----
#pragma unroll
        for (int ct = 0; ct < 8; ++ct) {
#pragma unroll
            for (int r = 0; r < 4; ++r) {
                float p = __expf(sacc[ct][r]);
                lsum[r] += p;
                int row = w * 16 + quad * 4 + r;
                int key = ct * 16 + l16;
                pl[buf][(key >> 3) * 512 + row * 8 + (key & 7)] = f2bf(p);
            }
        }
        __syncthreads();   // publish P[buf]; prev buf's readers also done

        // ---- O += P @ V  (wave w: cols w*64..+63) ----
#pragma unroll
        for (int kh = 0; kh < 4; ++kh) {
            bf16x8 pa[4];
#pragma unroll
            for (int mt = 0; mt < 4; ++mt)
                pa[mt] = *reinterpret_cast<const bf16x8*>(
                    &pl[buf][(kh * 4 + quad) * 512 + (mt * 16 + l16) * 8]);
#pragma unroll
            for (int nt = 0; nt < 4; ++nt)
#pragma unroll
                for (int mt = 0; mt < 4; ++mt)
                    oacc[mt][nt] = __builtin_amdgcn_mfma_f32_16x16x32_bf16(
                        pa[mt], vbr[nt][kh], oacc[mt][nt], 0, 0, 0);
        }
    }

    // ---- epilogue: reduce l, share across waves, normalized bf16 store ----
#pragma unroll
    for (int r = 0; r < 4; ++r) {
        float s = lsum[r];
        s += __shfl_xor(s, 1);
        s += __shfl_xor(s, 2);
        s += __shfl_xor(s, 4);
        s += __shfl_xor(s, 8);
        lsum[r] = s;
    }
    if (l16 == 0) {
#pragma unroll
        for (int r = 0; r < 4; ++r) {
            lfin[w * 16 + quad * 4 + r] = lsum[r];
            lpart[((size_t)ks << 14) + b * 4096 + qt * 64 + w * 16 +
                  quad * 4 + r] = lsum[r];
        }
    }
    __syncthreads();

#pragma unroll
    for (int mt = 0; mt < 4; ++mt) {
        f32x4 lv = *reinterpret_cast<const f32x4*>(&lfin[mt * 16 + quad * 4]);
        float inv[4];
#pragma unroll
        for (int r = 0; r < 4; ++r) inv[r] = 1.f / lv[r];
#pragma unroll
        for (int nt = 0; nt < 4; ++nt) {
            u16* op = obf + ((size_t)ks << 22) +
                (size_t)(b * 4096 + qt * 64 + mt * 16 + quad * 4) * 256 +
                w * 64 + nt * 16 + l16;
#pragma unroll
            for (int r = 0; r < 4; ++r)
                op[(size_t)r * 256] = f2bf(oacc[mt][nt][r] * inv[r]);
        }
    }
}

// ---------------------------------------------------------------------------
// final: out = x + (sum_s wgt_s * obf[s]) @ Wv + bv,  wgt_s = l_s / sum l.
// bf16 MFMA, no LDS. block = 32 rows; wave w = cols w*64..+63.
// ---------------------------------------------------------------------------
__global__ __launch_bounds__(256) void final_mfma2(
    const u16* __restrict__ obf, const float* __restrict__ lpart, int S,
    const u16* __restrict__ wT, const float* __restrict__ bvv,
    const float* __restrict__ x, float* __restrict__ out)
{
    const int t    = threadIdx.x;
    const int w    = t >> 6;
    const int lane = t & 63;
    const int quad = lane >> 4;
    const int l16  = lane & 15;
    const int m0   = blockIdx.x * 32;
    const int wb   = w * 64;

    // per-row combine weights (row = m0 + mt*16 + l16)
    float wgt[2][4];
#pragma unroll
    for (int mt = 0; mt < 2; ++mt) {
        int row = m0 + mt * 16 + l16;
        float ls[4];
        float tot = 0.f;
        for (int s = 0; s < S; ++s) {
            ls[s] = lpart[(size_t)s * 16384 + row];
            tot += ls[s];
        }
        float inv = 1.f / tot;
        for (int s = 0; s < S; ++s) wgt[mt][s] = ls[s] * inv;
    }

    f32x4 acc[2][4];
#pragma unroll
    for (int mt = 0; mt < 2; ++mt)
#pragma unroll
        for (int nt = 0; nt < 4; ++nt)
#pragma unroll
            for (int r = 0; r < 4; ++r) acc[mt][nt][r] = 0.f;

#pragma unroll 2
    for (int ks = 0; ks < 8; ++ks) {
        bf16x8 afrag[2];
#pragma unroll
        for (int mt = 0; mt < 2; ++mt) {
            size_t off = (size_t)(m0 + mt * 16 + l16) * 256 + ks * 32 + quad * 8;
            float f[8] = {0.f, 0.f, 0.f, 0.f, 0.f, 0.f, 0.f, 0.f};
            for (int s = 0; s < S; ++s) {
                bf16x8 v = *reinterpret_cast<const bf16x8*>(
                    obf + ((size_t)s << 22) + off);
                float ww = wgt[mt][s];
#pragma unroll
                for (int j = 0; j < 8; ++j) f[j] = fmaf(ww, bf2f(v[j]), f[j]);
            }
            bf16x8 a;
#pragma unroll
            for (int j = 0; j < 8; ++j) a[j] = (short)f2bf(f[j]);
            afrag[mt] = a;
        }
#pragma unroll
        for (int nt = 0; nt < 4; ++nt) {
            bf16x8 bfrag = *reinterpret_cast<const bf16x8*>(
                wT + (size_t)(320 + wb + nt * 16 + l16) * 256 +
                ks * 32 + quad * 8);
#pragma unroll
            for (int mt = 0; mt < 2; ++mt)
                acc[mt][nt] = __builtin_amdgcn_mfma_f32_16x16x32_bf16(
                    afrag[mt], bfrag, acc[mt][nt], 0, 0, 0);
        }
    }

#pragma unroll
    for (int nt = 0; nt < 4; ++nt) {
        int col = wb + nt * 16 + l16;
        float bias = bvv[col];
#pragma unroll
        for (int mt = 0; mt < 2; ++mt) {
            int row = m0 + mt * 16 + quad * 4;
#pragma unroll
            for (int r = 0; r < 4; ++r) {
                size_t off = (size_t)(row + r) * 256 + col;
                out[off] = acc[mt][nt][r] + bias + x[off];
            }
        }
    }
}

// ---------------------------------------------------------------------------
extern "C" void kernel_launch(void* const* d_in, const int* in_sizes, int n_in,
                              void* d_out, int out_size, void* d_ws, size_t ws_size,
                              hipStream_t stream)
{
    const float* x  = (const float*)d_in[0];
    const float* Wf = (const float*)d_in[1];
    const float* bf = (const float*)d_in[2];
    const float* Wg = (const float*)d_in[3];
    const float* bg = (const float*)d_in[4];
    const float* Wh = (const float*)d_in[5];
    const float* bh = (const float*)d_in[6];
    const float* Wv = (const float*)d_in[7];
    const float* bv = (const float*)d_in[8];
    float* out = (float*)d_out;

    const int M = 16384;

    const size_t base_b = (size_t)M * 64 * 2 + (size_t)4 * 256 * 4096 * 2 +
                          (size_t)576 * 256 * 2;
    const size_t per_s  = (size_t)M * 4 + (size_t)M * 256 * 2;
    int ksl = 0;
    if (ws_size >= base_b + 4 * per_s)      ksl = 2;
    else if (ws_size >= base_b + 2 * per_s) ksl = 1;
    const int S = 1 << ksl;

    u16*   fgbuf = (u16*)d_ws;
    u16*   hmt   = fgbuf + (size_t)M * 64;
    u16*   wT    = hmt + (size_t)4 * 256 * 4096;
    float* lpart = (float*)(wT + (size_t)576 * 256);
    u16*   obf   = (u16*)(lpart + (size_t)S * M);

    dim3 blk(256);

    prep_w<<<dim3(576), blk, 0, stream>>>(Wf, Wg, Wh, Wv, wT);
    proj_mfma<<<dim3(M / 32), blk, 0, stream>>>(x, wT, bf, bg, bh, fgbuf, hmt);
    attn3<<<dim3(256 * S), blk, 0, stream>>>(fgbuf, hmt, obf, lpart, ksl);
    final_mfma2<<<dim3(M / 32), blk, 0, stream>>>(
        obf, lpart, S, wT, bv, x, out);
}

// Round 7
// 202.710 us; speedup vs baseline: 1.1304x; 1.1304x over previous
//
#include <hip/hip_runtime.h>
#include <math.h>

// B=4, H=W=64, C=256, Ck=32, N=4096, M=B*N=16384
// ws: fg bf16 [16384][64] (f=cols0..31, g=cols32..63, g pre-scaled by log2e)
//   | hmt bf16 [4][256][4096] (channel-major)
//   | wT bf16 [576][256] (0..31 Wf^T, 32..63 Wg^T*log2e, 64..319 Wh^T, 320..575 Wv^T)
//   | lpart f32 [S][16384] | obf bf16 [S][16384][256] (per-split normalized)

typedef unsigned short u16;
typedef __attribute__((ext_vector_type(8))) short  bf16x8;
typedef __attribute__((ext_vector_type(4))) float  f32x4;

__device__ inline u16 f2bf(float x) {
    unsigned u = __float_as_uint(x);
    unsigned r = (u + 0x7fffu + ((u >> 16) & 1u)) >> 16;
    return (u16)r;
}

__device__ inline float bf2f(short s) {
    return __uint_as_float(((unsigned)(u16)s) << 16);
}

__device__ inline bf16x8 cvt8(float4 a, float4 b) {
    bf16x8 r;
    r[0] = (short)f2bf(a.x); r[1] = (short)f2bf(a.y);
    r[2] = (short)f2bf(a.z); r[3] = (short)f2bf(a.w);
    r[4] = (short)f2bf(b.x); r[5] = (short)f2bf(b.y);
    r[6] = (short)f2bf(b.z); r[7] = (short)f2bf(b.w);
    return r;
}

#define ASYNC_CP16(gp, lp)                                                     \
    __builtin_amdgcn_global_load_lds(                                          \
        (const __attribute__((address_space(1))) void*)(gp),                   \
        (__attribute__((address_space(3))) void*)(lp), 16, 0, 0)

#define LOG2E 1.4426950408889634f

// ---------------------------------------------------------------------------
// prep: pack weights transposed to bf16.  wT[n][k], n = concat col index.
// Wg rows are pre-scaled by log2e so softmax can use native exp2.
// ---------------------------------------------------------------------------
__global__ __launch_bounds__(256) void prep_w(
    const float* __restrict__ Wf, const float* __restrict__ Wg,
    const float* __restrict__ Wh, const float* __restrict__ Wv,
    u16* __restrict__ wT)
{
    const int n = blockIdx.x;
    const int k = threadIdx.x;
    float v;
    if (n < 32)        v = Wf[(size_t)k * 32 + n];
    else if (n < 64)   v = Wg[(size_t)k * 32 + n - 32] * LOG2E;
    else if (n < 320)  v = Wh[(size_t)k * 256 + n - 64];
    else               v = Wv[(size_t)k * 256 + n - 320];
    wT[(size_t)n * 256 + k] = f2bf(v);
}

// ---------------------------------------------------------------------------
// proj: Y[16384, 320] = x @ [Wf|Wg|Wh] + bias, bf16 MFMA, no LDS.
// block = 32 rows; wave w = cols w*80..+79 (5 n-tiles).
// cols 0..63 -> fg row-major; cols 64..319 -> hmt channel-major (8B stores).
// ---------------------------------------------------------------------------
__global__ __launch_bounds__(256) void proj_mfma(
    const float* __restrict__ x, const u16* __restrict__ wT,
    const float* __restrict__ bfv, const float* __restrict__ bgv,
    const float* __restrict__ bhv,
    u16* __restrict__ fg, u16* __restrict__ hmt)
{
    const int t    = threadIdx.x;
    const int w    = t >> 6;
    const int lane = t & 63;
    const int quad = lane >> 4;
    const int l16  = lane & 15;
    const int m0   = blockIdx.x * 32;
    const int wb   = w * 80;

    f32x4 acc[2][5];
#pragma unroll
    for (int mt = 0; mt < 2; ++mt)
#pragma unroll
        for (int nt = 0; nt < 5; ++nt)
#pragma unroll
            for (int r = 0; r < 4; ++r) acc[mt][nt][r] = 0.f;

#pragma unroll 2
    for (int ks = 0; ks < 8; ++ks) {
        bf16x8 afrag[2];
#pragma unroll
        for (int mt = 0; mt < 2; ++mt) {
            const float* xp = x + (size_t)(m0 + mt * 16 + l16) * 256 +
                              ks * 32 + quad * 8;
            float4 a0 = *reinterpret_cast<const float4*>(xp);
            float4 a1 = *reinterpret_cast<const float4*>(xp + 4);
            afrag[mt] = cvt8(a0, a1);
        }
#pragma unroll
        for (int nt = 0; nt < 5; ++nt) {
            bf16x8 bfrag = *reinterpret_cast<const bf16x8*>(
                wT + (size_t)(wb + nt * 16 + l16) * 256 + ks * 32 + quad * 8);
#pragma unroll
            for (int mt = 0; mt < 2; ++mt)
                acc[mt][nt] = __builtin_amdgcn_mfma_f32_16x16x32_bf16(
                    afrag[mt], bfrag, acc[mt][nt], 0, 0, 0);
        }
    }

    const int bb   = m0 >> 12;
    const int npix = m0 & 4095;
#pragma unroll
    for (int nt = 0; nt < 5; ++nt) {
        int col = wb + nt * 16 + l16;
        if (col < 64) {
            float bias = (col < 32) ? bfv[col] : bgv[col - 32] * LOG2E;
#pragma unroll
            for (int mt = 0; mt < 2; ++mt) {
                int row = m0 + mt * 16 + quad * 4;
#pragma unroll
                for (int r = 0; r < 4; ++r)
                    fg[(size_t)(row + r) * 64 + col] =
                        f2bf(acc[mt][nt][r] + bias);
            }
        } else {
            int c = col - 64;
            float bias = bhv[c];
#pragma unroll
            for (int mt = 0; mt < 2; ++mt) {
                int n0 = npix + mt * 16 + quad * 4;
                ushort4 hv;
                hv.x = f2bf(acc[mt][nt][0] + bias);
                hv.y = f2bf(acc[mt][nt][1] + bias);
                hv.z = f2bf(acc[mt][nt][2] + bias);
                hv.w = f2bf(acc[mt][nt][3] + bias);
                *reinterpret_cast<ushort4*>(
                    hmt + ((size_t)bb * 256 + c) * 4096 + n0) = hv;
            }
        }
    }
}

// ---------------------------------------------------------------------------
// Flash attention v4: attn2's staging structure + attn3's P layout + XCD
// batch-local swizzle + exp2 softmax.
//  block: (b, qt, ks). 64 queries, 128-key tiles, nkt = 32>>ksl tiles.
//  F staged in LDS via global_load_lds (dbuf) -> S never waits on vmcnt.
//  V direct to regs, issued with F-stage right after B1 -> single drain at B2.
//  P in [kblk][row][8] LDS layout (conflict-free b128 reads, 2-way writes).
//  XCD swizzle (ksl==1): batch pinned to an XCD pair so hmt+fg stay L2-local.
// ---------------------------------------------------------------------------
__global__ __launch_bounds__(256) void attn4(
    const u16* __restrict__ fg, const u16* __restrict__ hmt,
    u16* __restrict__ obf, float* __restrict__ lpart, int ksl)
{
    __shared__ u16 fl[2][4096];   // F dbuf: [ct(8)][quad(4)][l16(16)][8]
    __shared__ u16 pl[8192];      // P: [kblk(16)][row(64)][8]
    __shared__ float lfin[64];

    const int t    = threadIdx.x;
    const int w    = t >> 6;
    const int lane = t & 63;
    const int quad = lane >> 4;
    const int l16  = lane & 15;

    int b, qt, ks;
    if (ksl == 1) {
        // XCD-aware: xcd = blockIdx % 8 (assumed round-robin). Batch b on
        // XCD pair {2b, 2b+1} -> its hmt (2MB) + fg (0.5MB) stay L2-local.
        const int u   = blockIdx.x;
        const int xcd = u & 7;
        b = xcd >> 1;
        const int v = ((u >> 3) << 1) | (xcd & 1);   // 0..127
        qt = v >> 1;
        ks = v & 1;
    } else {
        ks = blockIdx.x & ((1 << ksl) - 1);
        qt = (blockIdx.x >> ksl) & 63;
        b  = blockIdx.x >> (ksl + 6);
    }
    const int nkt = 32 >> ksl;
    const int kt0 = ks * nkt;

    const size_t fg_base = (size_t)b * 4096 * 64;
    const size_t hm_base = (size_t)b * 256 * 4096;

    // G A-frag (pre-scaled by log2e): row qt*64 + w*16 + l16, ch quad*8..+7
    const bf16x8 gfrag = *reinterpret_cast<const bf16x8*>(
        fg + fg_base + (size_t)(qt * 64 + w * 16 + l16) * 64 + 32 + quad * 8);

    f32x4 oacc[4][4];
#pragma unroll
    for (int mt = 0; mt < 4; ++mt)
#pragma unroll
        for (int nt = 0; nt < 4; ++nt)
#pragma unroll
            for (int r = 0; r < 4; ++r) oacc[mt][nt][r] = 0.f;

    float lsum[4] = {0.f, 0.f, 0.f, 0.f};
    const f32x4 zero4 = {0.f, 0.f, 0.f, 0.f};

    // prologue: stage F(kt0) into buf 0 (wave w covers ct = 2w, 2w+1)
    {
        const u16* gp = fg + fg_base +
            (size_t)(kt0 * 128 + (2 * w) * 16 + l16) * 64 + quad * 8;
        ASYNC_CP16(gp, &fl[0][(2 * w) * 512]);
        ASYNC_CP16(gp + 16 * 64, &fl[0][(2 * w + 1) * 512]);
    }

    for (int it = 0; it < nkt; ++it) {
        const int kt  = kt0 + it;
        const int buf = it & 1;
        __syncthreads();   // B1: P consumed by prev PV; F(kt) resident

        // issue V(kt) reg loads + F(kt+1) stage back-to-back; both drain
        // (overlapped with S+exp below) at B2.
        bf16x8 vbr[4][4];
#pragma unroll
        for (int nt = 0; nt < 4; ++nt)
#pragma unroll
            for (int kh = 0; kh < 4; ++kh)
                vbr[nt][kh] = *reinterpret_cast<const bf16x8*>(
                    hmt + hm_base + (size_t)(w * 64 + nt * 16 + l16) * 4096 +
                    kt * 128 + kh * 32 + quad * 8);

        if (it + 1 < nkt) {
            const u16* gp = fg + fg_base +
                (size_t)((kt + 1) * 128 + (2 * w) * 16 + l16) * 64 + quad * 8;
            ASYNC_CP16(gp, &fl[buf ^ 1][(2 * w) * 512]);
            ASYNC_CP16(gp + 16 * 64, &fl[buf ^ 1][(2 * w + 1) * 512]);
        }

        // ---- S = G @ F^T from LDS (lgkm only, no vm wait) ----
        f32x4 sacc[8];
#pragma unroll
        for (int ct = 0; ct < 8; ++ct) {
            bf16x8 fb = *reinterpret_cast<const bf16x8*>(
                &fl[buf][ct * 512 + quad * 128 + l16 * 8]);
            sacc[ct] = __builtin_amdgcn_mfma_f32_16x16x32_bf16(
                gfrag, fb, zero4, 0, 0, 0);
        }

        // ---- p = exp2(s') (g pre-scaled by log2e), write P, accumulate l ----
#pragma unroll
        for (int ct = 0; ct < 8; ++ct) {
#pragma unroll
            for (int r = 0; r < 4; ++r) {
                float p = __builtin_amdgcn_exp2f(sacc[ct][r]);
                lsum[r] += p;
                int row = w * 16 + quad * 4 + r;
                int key = ct * 16 + l16;
                pl[(key >> 3) * 512 + row * 8 + (key & 7)] = f2bf(p);
            }
        }
        __syncthreads();   // B2: publish P; drains V(kt) + F(kt+1)

        // ---- O += P @ V  (wave w: cols w*64..+63) ----
#pragma unroll
        for (int kh = 0; kh < 4; ++kh) {
            bf16x8 pa[4];
#pragma unroll
            for (int mt = 0; mt < 4; ++mt)
                pa[mt] = *reinterpret_cast<const bf16x8*>(
                    &pl[(kh * 4 + quad) * 512 + (mt * 16 + l16) * 8]);
#pragma unroll
            for (int nt = 0; nt < 4; ++nt)
#pragma unroll
                for (int mt = 0; mt < 4; ++mt)
                    oacc[mt][nt] = __builtin_amdgcn_mfma_f32_16x16x32_bf16(
                        pa[mt], vbr[nt][kh], oacc[mt][nt], 0, 0, 0);
        }
    }

    // ---- epilogue: reduce l, share across waves, normalized bf16 store ----
#pragma unroll
    for (int r = 0; r < 4; ++r) {
        float s = lsum[r];
        s += __shfl_xor(s, 1);
        s += __shfl_xor(s, 2);
        s += __shfl_xor(s, 4);
        s += __shfl_xor(s, 8);
        lsum[r] = s;
    }
    if (l16 == 0) {
#pragma unroll
        for (int r = 0; r < 4; ++r) {
            lfin[w * 16 + quad * 4 + r] = lsum[r];
            lpart[((size_t)ks << 14) + b * 4096 + qt * 64 + w * 16 +
                  quad * 4 + r] = lsum[r];
        }
    }
    __syncthreads();

#pragma unroll
    for (int mt = 0; mt < 4; ++mt) {
        f32x4 lv = *reinterpret_cast<const f32x4*>(&lfin[mt * 16 + quad * 4]);
        float inv[4];
#pragma unroll
        for (int r = 0; r < 4; ++r) inv[r] = 1.f / lv[r];
#pragma unroll
        for (int nt = 0; nt < 4; ++nt) {
            u16* op = obf + ((size_t)ks << 22) +
                (size_t)(b * 4096 + qt * 64 + mt * 16 + quad * 4) * 256 +
                w * 64 + nt * 16 + l16;
#pragma unroll
            for (int r = 0; r < 4; ++r)
                op[(size_t)r * 256] = f2bf(oacc[mt][nt][r] * inv[r]);
        }
    }
}

// ---------------------------------------------------------------------------
// final: out = x + (sum_s wgt_s * obf[s]) @ Wv + bv,  wgt_s = l_s / sum l.
// bf16 MFMA, no LDS. block = 32 rows; wave w = cols w*64..+63.
// ---------------------------------------------------------------------------
__global__ __launch_bounds__(256) void final_mfma2(
    const u16* __restrict__ obf, const float* __restrict__ lpart, int S,
    const u16* __restrict__ wT, const float* __restrict__ bvv,
    const float* __restrict__ x, float* __restrict__ out)
{
    const int t    = threadIdx.x;
    const int w    = t >> 6;
    const int lane = t & 63;
    const int quad = lane >> 4;
    const int l16  = lane & 15;
    const int m0   = blockIdx.x * 32;
    const int wb   = w * 64;

    float wgt[2][4];
#pragma unroll
    for (int mt = 0; mt < 2; ++mt) {
        int row = m0 + mt * 16 + l16;
        float ls[4];
        float tot = 0.f;
        for (int s = 0; s < S; ++s) {
            ls[s] = lpart[(size_t)s * 16384 + row];
            tot += ls[s];
        }
        float inv = 1.f / tot;
        for (int s = 0; s < S; ++s) wgt[mt][s] = ls[s] * inv;
    }

    f32x4 acc[2][4];
#pragma unroll
    for (int mt = 0; mt < 2; ++mt)
#pragma unroll
        for (int nt = 0; nt < 4; ++nt)
#pragma unroll
            for (int r = 0; r < 4; ++r) acc[mt][nt][r] = 0.f;

#pragma unroll 2
    for (int ks = 0; ks < 8; ++ks) {
        bf16x8 afrag[2];
#pragma unroll
        for (int mt = 0; mt < 2; ++mt) {
            size_t off = (size_t)(m0 + mt * 16 + l16) * 256 + ks * 32 + quad * 8;
            float f[8] = {0.f, 0.f, 0.f, 0.f, 0.f, 0.f, 0.f, 0.f};
            for (int s = 0; s < S; ++s) {
                bf16x8 v = *reinterpret_cast<const bf16x8*>(
                    obf + ((size_t)s << 22) + off);
                float ww = wgt[mt][s];
#pragma unroll
                for (int j = 0; j < 8; ++j) f[j] = fmaf(ww, bf2f(v[j]), f[j]);
            }
            bf16x8 a;
#pragma unroll
            for (int j = 0; j < 8; ++j) a[j] = (short)f2bf(f[j]);
            afrag[mt] = a;
        }
#pragma unroll
        for (int nt = 0; nt < 4; ++nt) {
            bf16x8 bfrag = *reinterpret_cast<const bf16x8*>(
                wT + (size_t)(320 + wb + nt * 16 + l16) * 256 +
                ks * 32 + quad * 8);
#pragma unroll
            for (int mt = 0; mt < 2; ++mt)
                acc[mt][nt] = __builtin_amdgcn_mfma_f32_16x16x32_bf16(
                    afrag[mt], bfrag, acc[mt][nt], 0, 0, 0);
        }
    }

#pragma unroll
    for (int nt = 0; nt < 4; ++nt) {
        int col = wb + nt * 16 + l16;
        float bias = bvv[col];
#pragma unroll
        for (int mt = 0; mt < 2; ++mt) {
            int row = m0 + mt * 16 + quad * 4;
#pragma unroll
            for (int r = 0; r < 4; ++r) {
                size_t off = (size_t)(row + r) * 256 + col;
                out[off] = acc[mt][nt][r] + bias + x[off];
            }
        }
    }
}

// ---------------------------------------------------------------------------
extern "C" void kernel_launch(void* const* d_in, const int* in_sizes, int n_in,
                              void* d_out, int out_size, void* d_ws, size_t ws_size,
                              hipStream_t stream)
{
    const float* x  = (const float*)d_in[0];
    const float* Wf = (const float*)d_in[1];
    const float* bf = (const float*)d_in[2];
    const float* Wg = (const float*)d_in[3];
    const float* bg = (const float*)d_in[4];
    const float* Wh = (const float*)d_in[5];
    const float* bh = (const float*)d_in[6];
    const float* Wv = (const float*)d_in[7];
    const float* bv = (const float*)d_in[8];
    float* out = (float*)d_out;

    const int M = 16384;

    const size_t base_b = (size_t)M * 64 * 2 + (size_t)4 * 256 * 4096 * 2 +
                          (size_t)576 * 256 * 2;
    const size_t per_s  = (size_t)M * 4 + (size_t)M * 256 * 2;
    int ksl = (ws_size >= base_b + 2 * per_s) ? 1 : 0;   // S=2 preferred
    const int S = 1 << ksl;

    u16*   fgbuf = (u16*)d_ws;
    u16*   hmt   = fgbuf + (size_t)M * 64;
    u16*   wT    = hmt + (size_t)4 * 256 * 4096;
    float* lpart = (float*)(wT + (size_t)576 * 256);
    u16*   obf   = (u16*)(lpart + (size_t)S * M);

    dim3 blk(256);

    prep_w<<<dim3(576), blk, 0, stream>>>(Wf, Wg, Wh, Wv, wT);
    proj_mfma<<<dim3(M / 32), blk, 0, stream>>>(x, wT, bf, bg, bh, fgbuf, hmt);
    attn4<<<dim3(256 * S), blk, 0, stream>>>(fgbuf, hmt, obf, lpart, ksl);
    final_mfma2<<<dim3(M / 32), blk, 0, stream>>>(
        obf, lpart, S, wT, bv, x, out);
}